// Round 1
// baseline (1244.549 us; speedup 1.0000x reference)
//
#include <hip/hip_runtime.h>
#include <cstdint>
#include <cstddef>

#define BB 64
#define NN 4096

// ---------------------------------------------------------------------------
// Farthest point sampling. One block (256 threads) per batch. Points +
// running distances live in registers (NPER points per thread, static index).
// Exact-IEEE distance (no FMA contraction) to match the numpy reference's
// argmax selection bit-for-bit; ties broken toward lowest index via packing
// (dist_bits << 32) | (0xFFFFFFFF - idx) and taking max.
// ---------------------------------------------------------------------------
template<int NPER>
__global__ __launch_bounds__(256) void fps_kernel(
    const float* __restrict__ xyz, int n, int npoint,
    int* __restrict__ idx_out, float* __restrict__ sel_xyz)
{
  const int b = blockIdx.x;
  const int tid = threadIdx.x;
  const float* xb = xyz + (size_t)b * n * 3;

  float px[NPER], py[NPER], pz[NPER], dst[NPER];
#pragma unroll
  for (int k = 0; k < NPER; ++k) {
    int i = k * 256 + tid;
    if (i < n) { px[k] = xb[i*3+0]; py[k] = xb[i*3+1]; pz[k] = xb[i*3+2]; }
    else       { px[k] = 0.f; py[k] = 0.f; pz[k] = 0.f; }
    dst[k] = 1e10f;
  }

  __shared__ unsigned long long red[4];
  __shared__ int far_sh;
  int far = 0;

  for (int it = 0; it < npoint; ++it) {
    float cx = xb[far*3+0], cy = xb[far*3+1], cz = xb[far*3+2];
    if (tid == 0) {
      idx_out[b*npoint + it] = far;
      if (sel_xyz) {
        sel_xyz[(b*npoint+it)*3+0] = cx;
        sel_xyz[(b*npoint+it)*3+1] = cy;
        sel_xyz[(b*npoint+it)*3+2] = cz;
      }
    }
    unsigned long long best = 0ull;
#pragma unroll
    for (int k = 0; k < NPER; ++k) {
      int i = k * 256 + tid;
      float dx = px[k]-cx, dy = py[k]-cy, dz = pz[k]-cz;
      // ((dx*dx + dy*dy) + dz*dz) with forced IEEE ops (no contraction)
      float dd = __fadd_rn(__fadd_rn(__fmul_rn(dx,dx), __fmul_rn(dy,dy)),
                           __fmul_rn(dz,dz));
      float nd = fminf(dst[k], dd);
      dst[k] = nd;
      unsigned long long pk = ((unsigned long long)__float_as_uint(nd) << 32)
                            | (unsigned long long)(0xFFFFFFFFu - (unsigned)i);
      if (i < n && pk > best) best = pk;
    }
    // wave (64-lane) max reduce
#pragma unroll
    for (int o = 32; o > 0; o >>= 1) {
      unsigned long long other = __shfl_xor(best, o);
      if (other > best) best = other;
    }
    if ((tid & 63) == 0) red[tid >> 6] = best;
    __syncthreads();
    if (tid == 0) {
      unsigned long long m = red[0];
#pragma unroll
      for (int w = 1; w < 4; ++w) if (red[w] > m) m = red[w];
      far_sh = (int)(0xFFFFFFFFu - (unsigned)(m & 0xFFFFFFFFull));
    }
    __syncthreads();
    far = far_sh;
  }
}

// ---------------------------------------------------------------------------
// Confidence MLP for ALL points: conf = sigmoid(relu(x@cw1+cb1)@cw2+cb2)
// One thread per point; weights are thread-uniform (scalar-cached).
// ---------------------------------------------------------------------------
__global__ __launch_bounds__(256) void conf_kernel(
    const float* __restrict__ x,
    const float* __restrict__ cw1, const float* __restrict__ cb1,
    const float* __restrict__ cw2, const float* __restrict__ cb2,
    float* __restrict__ conf_out, int total)
{
  int i = blockIdx.x * 256 + threadIdx.x;
  if (i >= total) return;
  float x0 = x[i*3+0], x1 = x[i*3+1], x2 = x[i*3+2];
  float acc = cb2[0];
#pragma unroll
  for (int j = 0; j < 64; ++j) {
    float h = x0*cw1[j] + x1*cw1[64+j] + x2*cw1[128+j] + cb1[j];
    h = fmaxf(h, 0.f);
    acc += h * cw2[j];
  }
  conf_out[i] = 1.f / (1.f + expf(-acc));
}

// ---------------------------------------------------------------------------
// Fused per-sampled-point feature pipeline: for each of the B*500 sampled
// points, compute conf -> fc=[conf,x] -> l1(64) -> l2(256) = nf1.
// One 64-lane wave per point, 4 waves per block.
// ---------------------------------------------------------------------------
__global__ __launch_bounds__(256) void selfeat_kernel(
    const float* __restrict__ x, const int* __restrict__ idx1,
    const float* __restrict__ cw1, const float* __restrict__ cb1,
    const float* __restrict__ cw2, const float* __restrict__ cb2,
    const float* __restrict__ w1, const float* __restrict__ b1,
    const float* __restrict__ w2, const float* __restrict__ b2,
    float* __restrict__ nf1)
{
  int wid  = threadIdx.x >> 6;
  int lane = threadIdx.x & 63;
  int gw   = blockIdx.x * 4 + wid;           // point slot in [0, B*500)
  int b = gw / 500, s = gw % 500;
  int p = idx1[b*500 + s];
  const float* xp = x + ((size_t)b * NN + p) * 3;
  float x0 = xp[0], x1 = xp[1], x2 = xp[2];

  // conf
  float h = fmaxf(x0*cw1[lane] + x1*cw1[64+lane] + x2*cw1[128+lane] + cb1[lane], 0.f);
  float part = h * cw2[lane];
#pragma unroll
  for (int o = 32; o > 0; o >>= 1) part += __shfl_xor(part, o);
  float conf = 1.f / (1.f + expf(-(part + cb2[0])));

  // l1 (64)
  float l1v = fmaxf(conf*w1[lane] + x0*w1[64+lane] + x1*w1[128+lane]
                    + x2*w1[192+lane] + b1[lane], 0.f);
  __shared__ float l1s[4][64];
  l1s[wid][lane] = l1v;
  __syncthreads();

  // l2 (256): each lane computes 4 outputs
  float a0 = b2[lane], a1 = b2[64+lane], a2 = b2[128+lane], a3 = b2[192+lane];
#pragma unroll
  for (int k = 0; k < 64; ++k) {
    float lv = l1s[wid][k];
    const float* wr = w2 + k*256;
    a0 += lv * wr[lane];
    a1 += lv * wr[64+lane];
    a2 += lv * wr[128+lane];
    a3 += lv * wr[192+lane];
  }
  float* o = nf1 + (size_t)gw * 256;
  o[lane]      = fmaxf(a0, 0.f);
  o[64+lane]   = fmaxf(a1, 0.f);
  o[128+lane]  = fmaxf(a2, 0.f);
  o[192+lane]  = fmaxf(a3, 0.f);
}

// ---------------------------------------------------------------------------
// Generic f32 GEMM: C[M,N](ldc) = act(A[M,K] @ W[K,N] + bias), 64x64 tile,
// 256 threads, 4x4 per thread. M,N multiples of 64 (always true here);
// K edge zero-filled.
// ---------------------------------------------------------------------------
__global__ __launch_bounds__(256) void gemm_kernel(
    const float* __restrict__ A, const float* __restrict__ W,
    const float* __restrict__ bias, float* __restrict__ C,
    int M, int K, int Nc, int ldc, int act)
{
  __shared__ float As[16][68];   // [kk][m], padded row -> 16B aligned subrows
  __shared__ float Ws[16][64];   // [kk][n]
  int tid = threadIdx.x;
  int tx = tid & 15, ty = tid >> 4;
  int brow = blockIdx.y * 64, bcol = blockIdx.x * 64;

  float acc[4][4] = {{0.f}};

  for (int k0 = 0; k0 < K; k0 += 16) {
    {
      int m  = tid >> 4;      // 0..15
      int kk = tid & 15;
#pragma unroll
      for (int q = 0; q < 4; ++q) {
        int mm = m + q*16;
        float v = 0.f;
        if (k0 + kk < K) v = A[(size_t)(brow+mm)*K + k0 + kk];
        As[kk][mm] = v;
      }
      int kr = tid >> 6;      // 0..3
      int nn = tid & 63;
#pragma unroll
      for (int q = 0; q < 4; ++q) {
        int kkk = kr + q*4;
        float v = 0.f;
        if (k0 + kkk < K) v = W[(size_t)(k0+kkk)*Nc + bcol + nn];
        Ws[kkk][nn] = v;
      }
    }
    __syncthreads();
#pragma unroll
    for (int kk = 0; kk < 16; ++kk) {
      float a[4], bv[4];
#pragma unroll
      for (int i = 0; i < 4; ++i) a[i]  = As[kk][ty*4+i];
#pragma unroll
      for (int j = 0; j < 4; ++j) bv[j] = Ws[kk][tx*4+j];
#pragma unroll
      for (int i = 0; i < 4; ++i)
#pragma unroll
        for (int j = 0; j < 4; ++j) acc[i][j] += a[i]*bv[j];
    }
    __syncthreads();
  }

#pragma unroll
  for (int i = 0; i < 4; ++i) {
    int row = brow + ty*4 + i;
#pragma unroll
    for (int j = 0; j < 4; ++j) {
      int col = bcol + tx*4 + j;
      float v = acc[i][j] + bias[col];
      if (act) v = fmaxf(v, 0.f);
      C[(size_t)row*ldc + col] = v;
    }
  }
}

// copy (rows,3) xyz into first 3 columns of a (rows, ldc) matrix
__global__ __launch_bounds__(256) void copy_nx_kernel(
    const float* __restrict__ nx, float* __restrict__ dst, int rows, int ldc)
{
  int i = blockIdx.x * 256 + threadIdx.x;
  if (i >= rows * 3) return;
  int r = i / 3, c = i % 3;
  dst[(size_t)r*ldc + c] = nx[i];
}

// dst[b,s,c] = src[b, idx[b,s], c]
__global__ __launch_bounds__(256) void gather_kernel(
    const float* __restrict__ src, const int* __restrict__ idx,
    float* __restrict__ dst, int Bv, int Ss, int Sd, int C)
{
  int i = blockIdx.x * 256 + threadIdx.x;
  int total = Bv * Sd * C;
  if (i >= total) return;
  int c = i % C; int t = i / C; int s = t % Sd; int b = t / Sd;
  int p = idx[b*Sd + s];
  dst[i] = src[((size_t)b*Ss + p)*C + c];
}

// out[b,n] = max_s l8[b,s,n], s in [0,125)
__global__ __launch_bounds__(256) void maxpool_kernel(
    const float* __restrict__ l8, float* __restrict__ out)
{
  int i = blockIdx.x * 256 + threadIdx.x;
  if (i >= BB * 512) return;
  int b = i >> 9, n = i & 511;
  const float* p = l8 + (size_t)b * 125 * 512 + n;
  float m = p[0];
  for (int s = 1; s < 125; ++s) m = fmaxf(m, p[(size_t)s * 512]);
  out[(size_t)b*512 + n] = m;
}

// ---------------------------------------------------------------------------
extern "C" void kernel_launch(void* const* d_in, const int* in_sizes, int n_in,
                              void* d_out, int out_size, void* d_ws, size_t ws_size,
                              hipStream_t stream)
{
  const float* x    = (const float*)d_in[0];
  const float* cw1  = (const float*)d_in[1];
  const float* cb1  = (const float*)d_in[2];
  const float* cw2  = (const float*)d_in[3];
  const float* cb2  = (const float*)d_in[4];
  const float* w1   = (const float*)d_in[5];
  const float* b1   = (const float*)d_in[6];
  const float* w2   = (const float*)d_in[7];
  const float* b2   = (const float*)d_in[8];
  const float* w3   = (const float*)d_in[9];
  const float* b3   = (const float*)d_in[10];
  const float* w4   = (const float*)d_in[11];
  const float* b4   = (const float*)d_in[12];
  const float* w5   = (const float*)d_in[13];
  const float* b5   = (const float*)d_in[14];
  const float* w6   = (const float*)d_in[15];
  const float* b6   = (const float*)d_in[16];
  const float* pc1w = (const float*)d_in[17];
  const float* pc1b = (const float*)d_in[18];
  const float* pc2w = (const float*)d_in[19];
  const float* pc2b = (const float*)d_in[20];

  float* out      = (float*)d_out;          // (64,512) = 32768 floats
  float* conf_out = out + 64*512;           // (64,4096,1) = 262144 floats

  // ---- workspace carve-up (reused regions) ----
  char* ws = (char*)d_ws;
  size_t off = 0;
  auto alloc = [&](size_t bytes) -> void* {
    void* p = ws + off;
    off = (off + bytes + 255) & ~(size_t)255;
    return p;
  };
  int*   idx1 = (int*)  alloc((size_t)BB*500*4);
  int*   idx2 = (int*)  alloc((size_t)BB*250*4);
  int*   idx3 = (int*)  alloc((size_t)BB*125*4);
  float* nx1  = (float*)alloc((size_t)BB*500*3*4);
  float* nx2  = (float*)alloc((size_t)BB*250*3*4);
  float* R1   = (float*)alloc((size_t)BB*500*384*4);  // nf1 -> l5 -> l8
  float* R2   = (float*)alloc((size_t)BB*500*259*4);  // cat1 -> nf2 -> l7
  float* R3   = (float*)alloc((size_t)BB*500*256*4);  // l4 -> cat2
  float* S1   = (float*)alloc((size_t)BB*125*384*4);  // nf3
  (void)ws_size; (void)in_sizes; (void)n_in; (void)out_size;

  // ---- FPS chain (sequential dependencies) ----
  fps_kernel<16><<<BB, 256, 0, stream>>>(x,   NN,  500, idx1, nx1);
  fps_kernel<2> <<<BB, 256, 0, stream>>>(nx1, 500, 250, idx2, nx2);
  fps_kernel<1> <<<BB, 256, 0, stream>>>(nx2, 250, 125, idx3, nullptr);

  // ---- conf for all points (output 1) ----
  conf_kernel<<<(BB*NN + 255)/256, 256, 0, stream>>>(x, cw1, cb1, cw2, cb2,
                                                     conf_out, BB*NN);

  // ---- fused conf/l1/l2 for the 32000 sampled points -> nf1 (R1) ----
  selfeat_kernel<<<BB*500/4, 256, 0, stream>>>(x, idx1, cw1, cb1, cw2, cb2,
                                               w1, b1, w2, b2, R1);

  // l3 = nf1 @ pc1w + pc1b  -> cat1 cols 3.. (R2, ldc=259)
  gemm_kernel<<<dim3(256/64, BB*500/64), 256, 0, stream>>>(
      R1, pc1w, pc1b, R2 + 3, BB*500, 256, 256, 259, 0);
  copy_nx_kernel<<<(BB*500*3 + 255)/256, 256, 0, stream>>>(nx1, R2, BB*500, 259);

  // l4 = relu(cat1 @ w3 + b3) -> R3 (32000 x 256)
  gemm_kernel<<<dim3(256/64, BB*500/64), 256, 0, stream>>>(
      R2, w3, b3, R3, BB*500, 259, 256, 256, 1);

  // l5 = relu(l4 @ w4 + b4) -> R1 (32000 x 384)
  gemm_kernel<<<dim3(384/64, BB*500/64), 256, 0, stream>>>(
      R3, w4, b4, R1, BB*500, 256, 384, 384, 1);

  // nf2 = l5[idx2] -> R2 (16000 x 384)
  gather_kernel<<<(BB*250*384 + 255)/256, 256, 0, stream>>>(
      R1, idx2, R2, BB, 500, 250, 384);

  // l6 = nf2 @ pc2w + pc2b -> cat2 cols 3.. (R3, ldc=387)
  gemm_kernel<<<dim3(384/64, BB*250/64), 256, 0, stream>>>(
      R2, pc2w, pc2b, R3 + 3, BB*250, 384, 384, 387, 0);
  copy_nx_kernel<<<(BB*250*3 + 255)/256, 256, 0, stream>>>(nx2, R3, BB*250, 387);

  // l7 = relu(cat2 @ w5 + b5) -> R2 (16000 x 384)
  gemm_kernel<<<dim3(384/64, BB*250/64), 256, 0, stream>>>(
      R3, w5, b5, R2, BB*250, 387, 384, 384, 1);

  // nf3 = l7[idx3] -> S1 (8000 x 384)
  gather_kernel<<<(BB*125*384 + 255)/256, 256, 0, stream>>>(
      R2, idx3, S1, BB, 250, 125, 384);

  // l8 = relu(nf3 @ w6 + b6) -> R1 (8000 x 512)
  gemm_kernel<<<dim3(512/64, BB*125/64), 256, 0, stream>>>(
      S1, w6, b6, R1, BB*125, 384, 512, 512, 1);

  // out = max over s
  maxpool_kernel<<<(BB*512 + 255)/256, 256, 0, stream>>>(R1, out);
}